// Round 2
// baseline (71.421 us; speedup 1.0000x reference)
//
#include <hip/hip_runtime.h>

#define NP      4096
#define NQ      32768
#define KNN     32
#define RADIUS  0.1f
#define R2      (RADIUS * RADIUS)
#define NCELLS  1000          // 10x10x10 grid, cell edge = RADIUS
#define TPQ     8             // threads per query

// ws layout (bytes):
//   +0      int   rareCount
//   +256    int   rareList[2048]
//   +8448   int   cellStart[1001]
//   +16384  float4 sortedP[4096]          (total 81920 B)

// ---------------- Kernel A: bin particles (single block) ----------------
__global__ __launch_bounds__(1024) void bin_kernel(
    const float* __restrict__ pc,
    int* __restrict__ rareCount,
    int* __restrict__ cellStart,
    float4* __restrict__ sortedP)
{
    __shared__ int hist[NCELLS];
    __shared__ int cursor[NCELLS];
    __shared__ int scanb[1024];
    __shared__ unsigned short cid[NP];

    const int tid = threadIdx.x;
    if (tid < NCELLS) hist[tid] = 0;
    __syncthreads();

    for (int i = tid; i < NP; i += 1024) {
        float x = pc[3*i], y = pc[3*i+1], z = pc[3*i+2];
        int cx = min(max((int)(x * 10.f), 0), 9);
        int cy = min(max((int)(y * 10.f), 0), 9);
        int cz = min(max((int)(z * 10.f), 0), 9);
        int c  = (cx * 10 + cy) * 10 + cz;
        cid[i] = (unsigned short)c;
        atomicAdd(&hist[c], 1);
    }
    __syncthreads();

    // inclusive Hillis-Steele scan over 1024 slots (1000 real)
    scanb[tid] = (tid < NCELLS) ? hist[tid] : 0;
    __syncthreads();
    for (int off = 1; off < 1024; off <<= 1) {
        int add = (tid >= off) ? scanb[tid - off] : 0;
        __syncthreads();
        scanb[tid] += add;
        __syncthreads();
    }
    if (tid < NCELLS) {
        int st = (tid == 0) ? 0 : scanb[tid - 1];
        cursor[tid]    = st;
        cellStart[tid] = st;
    }
    if (tid == 0) { cellStart[NCELLS] = NP; rareCount[0] = 0; }
    __syncthreads();

    for (int i = tid; i < NP; i += 1024) {
        int c = cid[i];
        int pos = atomicAdd(&cursor[c], 1);
        float x = pc[3*i], y = pc[3*i+1], z = pc[3*i+2];
        sortedP[pos] = make_float4(x, y, z, __int_as_float(i));
    }
}

// ---------------- Kernel B: per-query neighborhood accumulation ----------------
__global__ __launch_bounds__(256) void query_kernel(
    const float* __restrict__ rp,
    const float4* __restrict__ sortedP,
    const int* __restrict__ cellStartG,
    int* __restrict__ rareCount,
    int* __restrict__ rareList,
    float* __restrict__ out)
{
    __shared__ int cs[NCELLS + 1];
    const int tid = threadIdx.x;
    for (int c = tid; c < NCELLS + 1; c += 256) cs[c] = cellStartG[c];
    __syncthreads();

    const int gt = blockIdx.x * 256 + tid;
    const int qi = gt >> 3;        // query index
    const int s  = gt & 7;         // sub-thread within octet

    const float qx = rp[3*qi], qy = rp[3*qi+1], qz = rp[3*qi+2];
    const int cx = min(max((int)(qx * 10.f), 0), 9);
    const int cy = min(max((int)(qy * 10.f), 0), 9);
    const int cz = min(max((int)(qz * 10.f), 0), 9);

    float sw = 0.f, swx = 0.f, swy = 0.f, swz = 0.f;
    int   cnt = 0;

    int ci = 0;
    for (int xc = cx - 1; xc <= cx + 1; ++xc)
    for (int yc = cy - 1; yc <= cy + 1; ++yc)
    for (int zc = cz - 1; zc <= cz + 1; ++zc, ++ci) {
        if ((ci & 7) != s) continue;                    // partition 27 cells over octet
        if (xc < 0 || xc > 9 || yc < 0 || yc > 9 || zc < 0 || zc > 9) continue;
        const int cell = (xc * 10 + yc) * 10 + zc;
        const int j1 = cs[cell + 1];
        for (int j = cs[cell]; j < j1; ++j) {
            float4 pp = sortedP[j];
            float dx = pp.x - qx, dy = pp.y - qy, dz = pp.z - qz;
            float d2 = fmaf(dx, dx, fmaf(dy, dy, dz * dz));
            float d  = sqrtf(d2);
            float w  = fmaxf(fmaf(d2 * d, -1000.f, 1.f), 0.f);  // zero outside ball
            sw  += w;
            swx = fmaf(w, pp.x, swx);
            swy = fmaf(w, pp.y, swy);
            swz = fmaf(w, pp.z, swz);
            cnt += (d2 <= R2) ? 1 : 0;
        }
    }

    // octet reduce (fixed order -> deterministic up to list order)
    #pragma unroll
    for (int m = 1; m <= 4; m <<= 1) {
        sw  += __shfl_xor(sw,  m);
        swx += __shfl_xor(swx, m);
        swy += __shfl_xor(swy, m);
        swz += __shfl_xor(swz, m);
        cnt += __shfl_xor(cnt, m);
    }

    if (s == 0) {
        if (cnt <= KNN) {
            // masked slots gather particle 0, get zeroed -> nn_d = ||q||
            float nq2 = fmaf(qx, qx, fmaf(qy, qy, qz * qz));
            float nq  = sqrtf(nq2);
            float w0  = fmaxf(fmaf(nq2 * nq, -1000.f, 1.f), 0.f);
            float dens = sw + (float)(KNN - cnt) * w0;
            float inv  = 1.f / (dens + 1e-12f);
            ((float4*)out)[qi] = make_float4(swx * inv, swy * inv, swz * inv, dens);
        } else {
            int pos = atomicAdd(rareCount, 1);
            if (pos < 2048) rareList[pos] = qi;
        }
    }
}

// ---------------- Kernel C: exact top-K for rare cnt>K queries ----------------
__global__ __launch_bounds__(256) void rare_kernel(
    const float* __restrict__ rp,
    const float* __restrict__ pc,
    const int* __restrict__ rareCount,
    const int* __restrict__ rareList,
    float* __restrict__ out)
{
    __shared__ float sd2[512];
    __shared__ int   sid[512];
    __shared__ int   scnt;
    __shared__ float ord[KNN][4];

    const int n = rareCount[0];
    for (int r = blockIdx.x; r < n; r += gridDim.x) {
        const int fq = rareList[r];
        const float fx = rp[3*fq], fy = rp[3*fq+1], fz = rp[3*fq+2];
        if (threadIdx.x == 0) scnt = 0;
        __syncthreads();
        for (int p = threadIdx.x; p < NP; p += 256) {
            float dx = pc[3*p]   - fx;
            float dy = pc[3*p+1] - fy;
            float dz = pc[3*p+2] - fz;
            float d2 = fmaf(dx, dx, fmaf(dy, dy, dz * dz));
            if (d2 <= R2) {
                int pos = atomicAdd(&scnt, 1);
                if (pos < 512) { sd2[pos] = d2; sid[pos] = p; }
            }
        }
        __syncthreads();
        const int ne = (scnt < 512) ? scnt : 512;
        // exact rank by (d2, original idx) lexicographic == lax.top_k stable ties
        for (int e = threadIdx.x; e < ne; e += 256) {
            float myd = sd2[e];
            int   myi = sid[e];
            int rank = 0;
            for (int j = 0; j < ne; ++j) {
                float dj = sd2[j];
                int   ij = sid[j];
                rank += (dj < myd || (dj == myd && ij < myi)) ? 1 : 0;
            }
            if (rank < KNN) {
                float px = pc[3*myi], py = pc[3*myi+1], pz = pc[3*myi+2];
                float d = sqrtf(myd);
                float w = fmaxf(fmaf(myd * d, -1000.f, 1.f), 0.f);
                ord[rank][0] = w;
                ord[rank][1] = w * px;
                ord[rank][2] = w * py;
                ord[rank][3] = w * pz;
            }
        }
        __syncthreads();
        if (threadIdx.x == 0) {
            float t0 = 0.f, t1 = 0.f, t2 = 0.f, t3 = 0.f;
            #pragma unroll
            for (int k = 0; k < KNN; ++k) {
                t0 += ord[k][0]; t1 += ord[k][1]; t2 += ord[k][2]; t3 += ord[k][3];
            }
            float inv = 1.f / (t0 + 1e-12f);   // cnt>K: no masked slots, m=0
            ((float4*)out)[fq] = make_float4(t1 * inv, t2 * inv, t3 * inv, t0);
        }
        __syncthreads();
    }
}

extern "C" void kernel_launch(void* const* d_in, const int* in_sizes, int n_in,
                              void* d_out, int out_size, void* d_ws, size_t ws_size,
                              hipStream_t stream) {
    const float* rp = (const float*)d_in[0];   // [512,64,3]
    const float* pc = (const float*)d_in[1];   // [4096,3]
    float*       out = (float*)d_out;          // [512,64,4]

    int*    wsI       = (int*)d_ws;
    int*    rareCount = wsI;                                   // +0
    int*    rareList  = (int*)((char*)d_ws + 256);             // +256
    int*    cellStart = (int*)((char*)d_ws + 8448);            // +8448
    float4* sortedP   = (float4*)((char*)d_ws + 16384);        // +16384

    bin_kernel  <<<1,    1024, 0, stream>>>(pc, rareCount, cellStart, sortedP);
    query_kernel<<<NQ * TPQ / 256, 256, 0, stream>>>(rp, sortedP, cellStart,
                                                     rareCount, rareList, out);
    rare_kernel <<<16,   256, 0, stream>>>(rp, pc, rareCount, rareList, out);
}

// Round 3
// 40.652 us; speedup vs baseline: 1.7569x; 1.7569x over previous
//
#include <hip/hip_runtime.h>

#define NP      4096
#define NQ      32768
#define KNN     32
#define RADIUS  0.1f
#define R2      (RADIUS * RADIUS)
#define NCELLS  1000          // 10x10x10 grid, cell edge = RADIUS
#define CAP_P   24            // max particles/cell  (lambda=4.1,  +10 sigma)
#define CAP_Q   96            // max queries/cell    (lambda=32.8, +11 sigma)
#define NBR_CAP 704           // >= 27*CAP_P = 648

// ws layout (bytes):
//   +0       int    pCount[1000]        (zeroed each call)
//   +4096    int    qCount[1000]        (zeroed each call)
//   +8192    ushort qIdx[1000*96]
//   +200704  float4 pBucket[1000*24]    -> total 584704 B
#define WS_NEEDED 584704u

// ---------------- Kernel A: bin particles + queries into buckets ----------------
__global__ __launch_bounds__(256) void bin_kernel(
    const float* __restrict__ rp, const float* __restrict__ pc,
    int* __restrict__ pCount, int* __restrict__ qCount,
    unsigned short* __restrict__ qIdx, float4* __restrict__ pBucket)
{
    const int gt = blockIdx.x * 256 + threadIdx.x;
    const int stride = gridDim.x * 256;
    for (int i = gt; i < NP; i += stride) {
        float x = pc[3*i], y = pc[3*i+1], z = pc[3*i+2];
        int cx = min(max((int)(x * 10.f), 0), 9);
        int cy = min(max((int)(y * 10.f), 0), 9);
        int cz = min(max((int)(z * 10.f), 0), 9);
        int c  = (cx * 10 + cy) * 10 + cz;
        int pos = atomicAdd(&pCount[c], 1);
        if (pos < CAP_P) pBucket[c * CAP_P + pos] = make_float4(x, y, z, __int_as_float(i));
    }
    for (int i = gt; i < NQ; i += stride) {
        float x = rp[3*i], y = rp[3*i+1], z = rp[3*i+2];
        int cx = min(max((int)(x * 10.f), 0), 9);
        int cy = min(max((int)(y * 10.f), 0), 9);
        int cz = min(max((int)(z * 10.f), 0), 9);
        int c  = (cx * 10 + cy) * 10 + cz;
        int pos = atomicAdd(&qCount[c], 1);
        if (pos < CAP_Q) qIdx[c * CAP_Q + pos] = (unsigned short)i;
    }
}

// ---------------- Kernel B: one block per cell, LDS-broadcast accumulation ----------------
__global__ __launch_bounds__(128) void cell_kernel(
    const float* __restrict__ rp,
    const int* __restrict__ pCount, const int* __restrict__ qCount,
    const unsigned short* __restrict__ qIdx, const float4* __restrict__ pBucket,
    float* __restrict__ out)
{
    __shared__ float4 nbr[NBR_CAP];     // 27-neighborhood particles, contiguous
    __shared__ float  sd2[NBR_CAP];     // rare-path d2 table
    __shared__ int    counts[27], ncell[27], offs[28];
    __shared__ int    nrare;
    __shared__ unsigned short rlist[CAP_Q];
    __shared__ float  ord[KNN][4];

    const int c   = blockIdx.x;
    const int tid = threadIdx.x;
    const int cz = c % 10, cy = (c / 10) % 10, cx = c / 100;

    // neighbor-cell counts
    if (tid < 27) {
        int dx = tid / 9 - 1, dy = (tid / 3) % 3 - 1, dz = tid % 3 - 1;
        int nx = cx + dx, ny = cy + dy, nz = cz + dz;
        bool valid = (unsigned)nx < 10u && (unsigned)ny < 10u && (unsigned)nz < 10u;
        int nc = valid ? (nx * 10 + ny) * 10 + nz : 0;
        ncell[tid]  = nc;
        counts[tid] = valid ? min(pCount[nc], CAP_P) : 0;
    }
    if (tid == 0) nrare = 0;
    __syncthreads();
    if (tid == 0) {
        int s = 0;
        for (int i = 0; i < 27; ++i) { offs[i] = s; s += counts[i]; }
        offs[27] = s;
    }
    __syncthreads();
    const int M = offs[27];

    // stage neighborhood into LDS (4 threads per neighbor cell)
    if (tid < 108) {
        int ci = tid >> 2, sub = tid & 3;
        int cnt = counts[ci], base = offs[ci], nc = ncell[ci];
        for (int e = sub; e < cnt; e += 4)
            nbr[base + e] = pBucket[nc * CAP_P + e];
    }
    __syncthreads();

    // ---- fast path: 4 threads per query, LDS broadcast reads ----
    const int nq = min(qCount[c], CAP_Q);
    const int sub = tid & 3;
    for (int i = tid >> 2; i < nq; i += 32) {
        const int qi = qIdx[c * CAP_Q + i];
        const float qx = rp[3*qi], qy = rp[3*qi+1], qz = rp[3*qi+2];
        float sw = 0.f, swx = 0.f, swy = 0.f, swz = 0.f;
        int cnt = 0;
        for (int j = sub; j < M; j += 4) {
            float4 pp = nbr[j];
            float dx = pp.x - qx, dy = pp.y - qy, dz = pp.z - qz;
            float d2 = fmaf(dx, dx, fmaf(dy, dy, dz * dz));
            float d  = sqrtf(d2);
            float w  = fmaxf(fmaf(d2 * d, -1000.f, 1.f), 0.f);  // 1-(d/R)^3, 0 outside
            sw  += w;
            swx = fmaf(w, pp.x, swx);
            swy = fmaf(w, pp.y, swy);
            swz = fmaf(w, pp.z, swz);
            cnt += (d2 <= R2) ? 1 : 0;
        }
        #pragma unroll
        for (int m = 1; m <= 2; m <<= 1) {
            sw  += __shfl_xor(sw,  m);
            swx += __shfl_xor(swx, m);
            swy += __shfl_xor(swy, m);
            swz += __shfl_xor(swz, m);
            cnt += __shfl_xor(cnt, m);
        }
        if (sub == 0) {
            if (cnt <= KNN) {
                // masked slots gather particle 0 then zero -> nn_d = ||q||
                float nq2 = fmaf(qx, qx, fmaf(qy, qy, qz * qz));
                float nqd = sqrtf(nq2);
                float w0  = fmaxf(fmaf(nq2 * nqd, -1000.f, 1.f), 0.f);
                float dens = sw + (float)(KNN - cnt) * w0;
                float inv  = 1.f / (dens + 1e-12f);
                ((float4*)out)[qi] = make_float4(swx * inv, swy * inv, swz * inv, dens);
            } else {
                int pos = atomicAdd(&nrare, 1);
                rlist[pos] = (unsigned short)qi;   // cap = CAP_Q, cannot overflow
            }
        }
    }
    __syncthreads();

    // ---- rare path (cnt > K): exact top-K by (d2, idx) lexicographic rank ----
    for (int r = 0; r < nrare; ++r) {          // block-uniform
        const int qi = rlist[r];
        const float qx = rp[3*qi], qy = rp[3*qi+1], qz = rp[3*qi+2];
        for (int j = tid; j < M; j += 128) {
            float4 pp = nbr[j];
            float dx = pp.x - qx, dy = pp.y - qy, dz = pp.z - qz;
            sd2[j] = fmaf(dx, dx, fmaf(dy, dy, dz * dz));
        }
        __syncthreads();
        for (int j = tid; j < M; j += 128) {
            float dj = sd2[j];
            if (dj <= R2) {
                int ij = __float_as_int(nbr[j].w);
                int rank = 0;
                for (int k = 0; k < M; ++k) {
                    float dk = sd2[k];
                    int   ik = __float_as_int(nbr[k].w);
                    rank += (dk < dj || (dk == dj && ik < ij)) ? 1 : 0;
                }
                if (rank < KNN) {               // exactly K entries land here
                    float4 pp = nbr[j];
                    float d = sqrtf(dj);
                    float w = fmaxf(fmaf(dj * d, -1000.f, 1.f), 0.f);
                    ord[rank][0] = w;
                    ord[rank][1] = w * pp.x;
                    ord[rank][2] = w * pp.y;
                    ord[rank][3] = w * pp.z;
                }
            }
        }
        __syncthreads();
        if (tid == 0) {
            float t0 = 0.f, t1 = 0.f, t2 = 0.f, t3 = 0.f;
            #pragma unroll
            for (int k = 0; k < KNN; ++k) {
                t0 += ord[k][0]; t1 += ord[k][1]; t2 += ord[k][2]; t3 += ord[k][3];
            }
            float inv = 1.f / (t0 + 1e-12f);    // cnt>K: m=0, no masked slots
            ((float4*)out)[qi] = make_float4(t1 * inv, t2 * inv, t3 * inv, t0);
        }
        __syncthreads();
    }
}

// ---------------- Fallback (validated round-1 monolithic) if ws too small ----------------
#define BLKQ   64
#define NWAVE  8
#define CHUNK  (NP / NWAVE)
#define THREADS (BLKQ * NWAVE)

__global__ __launch_bounds__(THREADS) void knn_smooth_kernel(
    const float* __restrict__ rp, const float* __restrict__ pc, float* __restrict__ out)
{
    __shared__ float4 sp[NP];
    __shared__ float  red[5][NWAVE][BLKQ];
    __shared__ int    sflag[BLKQ];
    __shared__ int    scnt;
    __shared__ float  ord[KNN][4];

    const int tid = threadIdx.x, lane = tid & 63, wv = tid >> 6, blk = blockIdx.x;
    float* spf = (float*)sp;
    for (int i = tid; i < NP * 3; i += THREADS) {
        int p = i / 3, ccc = i - 3 * p;
        spf[4 * p + ccc] = pc[i];
    }
    __syncthreads();
    const int q = blk * BLKQ + lane;
    const float qx = rp[3*q], qy = rp[3*q+1], qz = rp[3*q+2];
    float sw = 0.f, swx = 0.f, swy = 0.f, swz = 0.f; int cnt = 0;
    const int p0 = wv * CHUNK;
    #pragma unroll 4
    for (int p = p0; p < p0 + CHUNK; ++p) {
        float4 pp = sp[p];
        float dx = pp.x - qx, dy = pp.y - qy, dz = pp.z - qz;
        float d2 = fmaf(dx, dx, fmaf(dy, dy, dz * dz));
        if (d2 <= R2) {
            float d = sqrtf(d2);
            float w = fmaxf(fmaf(d2 * d, -1000.f, 1.f), 0.f);
            cnt += 1; sw += w;
            swx = fmaf(w, pp.x, swx); swy = fmaf(w, pp.y, swy); swz = fmaf(w, pp.z, swz);
        }
    }
    red[0][wv][lane] = sw; red[1][wv][lane] = swx; red[2][wv][lane] = swy;
    red[3][wv][lane] = swz; red[4][wv][lane] = (float)cnt;
    __syncthreads();
    if (tid < BLKQ) {
        float tsw = 0.f, tswx = 0.f, tswy = 0.f, tswz = 0.f; int tc = 0;
        #pragma unroll
        for (int w = 0; w < NWAVE; ++w) {
            tsw += red[0][w][tid]; tswx += red[1][w][tid]; tswy += red[2][w][tid];
            tswz += red[3][w][tid]; tc += (int)red[4][w][tid];
        }
        int flagged = (tc > KNN) ? 1 : 0;
        sflag[tid] = flagged;
        if (!flagged) {
            float nq2 = fmaf(qx, qx, fmaf(qy, qy, qz * qz));
            float nqd = sqrtf(nq2);
            float w0 = fmaxf(fmaf(nq2 * nqd, -1000.f, 1.f), 0.f);
            float dens = tsw + (float)(KNN - tc) * w0;
            float inv = 1.f / (dens + 1e-12f);
            ((float4*)out)[q] = make_float4(tswx * inv, tswy * inv, tswz * inv, dens);
        }
    }
    __syncthreads();
    float* sd2 = &red[0][0][0];
    int*   sid = (int*)(sd2 + 1024);
    for (int f = 0; f < BLKQ; ++f) {
        if (!sflag[f]) continue;
        if (tid == 0) scnt = 0;
        __syncthreads();
        const int fq = blk * BLKQ + f;
        const float fx = rp[3*fq], fy = rp[3*fq+1], fz = rp[3*fq+2];
        for (int p = tid; p < NP; p += THREADS) {
            float4 pp = sp[p];
            float dx = pp.x - fx, dy = pp.y - fy, dz = pp.z - fz;
            float d2 = fmaf(dx, dx, fmaf(dy, dy, dz * dz));
            if (d2 <= R2) {
                int pos = atomicAdd(&scnt, 1);
                if (pos < 1024) { sd2[pos] = d2; sid[pos] = p; }
            }
        }
        __syncthreads();
        const int ne = (scnt < 1024) ? scnt : 1024;
        for (int e = tid; e < ne; e += THREADS) {
            float myd = sd2[e]; int myi = sid[e]; int rank = 0;
            for (int j = 0; j < ne; ++j) {
                float dj = sd2[j]; int ij = sid[j];
                rank += (dj < myd || (dj == myd && ij < myi)) ? 1 : 0;
            }
            if (rank < KNN) {
                float4 pp = sp[myi];
                float d = sqrtf(myd);
                float w = fmaxf(fmaf(myd * d, -1000.f, 1.f), 0.f);
                ord[rank][0] = w; ord[rank][1] = w * pp.x;
                ord[rank][2] = w * pp.y; ord[rank][3] = w * pp.z;
            }
        }
        __syncthreads();
        if (tid == 0) {
            float t0 = 0.f, t1 = 0.f, t2 = 0.f, t3 = 0.f;
            #pragma unroll
            for (int k = 0; k < KNN; ++k) {
                t0 += ord[k][0]; t1 += ord[k][1]; t2 += ord[k][2]; t3 += ord[k][3];
            }
            float inv = 1.f / (t0 + 1e-12f);
            ((float4*)out)[fq] = make_float4(t1 * inv, t2 * inv, t3 * inv, t0);
        }
        __syncthreads();
    }
}

extern "C" void kernel_launch(void* const* d_in, const int* in_sizes, int n_in,
                              void* d_out, int out_size, void* d_ws, size_t ws_size,
                              hipStream_t stream) {
    const float* rp  = (const float*)d_in[0];   // [512,64,3]
    const float* pc  = (const float*)d_in[1];   // [4096,3]
    float*       out = (float*)d_out;           // [512,64,4]

    if (ws_size < WS_NEEDED) {
        knn_smooth_kernel<<<NQ / BLKQ, THREADS, 0, stream>>>(rp, pc, out);
        return;
    }

    int*            pCount  = (int*)d_ws;                             // +0
    int*            qCount  = (int*)((char*)d_ws + 4096);             // +4096
    unsigned short* qIdx    = (unsigned short*)((char*)d_ws + 8192);  // +8192
    float4*         pBucket = (float4*)((char*)d_ws + 200704);        // +200704

    hipMemsetAsync(d_ws, 0, 8192, stream);
    bin_kernel <<<64,   256, 0, stream>>>(rp, pc, pCount, qCount, qIdx, pBucket);
    cell_kernel<<<NCELLS, 128, 0, stream>>>(rp, pCount, qCount, qIdx, pBucket, out);
}

// Round 4
// 40.298 us; speedup vs baseline: 1.7723x; 1.0088x over previous
//
#include <hip/hip_runtime.h>

#define NP      4096
#define NQ      32768
#define KNN     32
#define RADIUS  0.1f
#define R2      (RADIUS * RADIUS)
#define NCELLS  1000          // 10x10x10 grid, cell edge = RADIUS
#define CAP_P   24            // max particles/cell  (lambda=4.1,  +10 sigma)
#define CAP_Q   96            // max queries/cell    (lambda=32.8, +11 sigma)
#define NBR_CAP 704           // >= 27*CAP_P = 648

// ws layout (bytes):
//   +0       int    pCount[1000]        (zeroed by zero_kernel each call)
//   +4096    int    qCount[1000]        (zeroed by zero_kernel each call)
//   +8192    ushort qIdx[1000*96]
//   +200704  float4 pBucket[1000*24]    -> total 584704 B
#define WS_NEEDED 584704u

// ---------------- Kernel 0: zero the 8 KB of count arrays (replaces memset) ----------------
__global__ __launch_bounds__(512) void zero_kernel(int4* __restrict__ p)
{
    p[threadIdx.x] = make_int4(0, 0, 0, 0);   // 512 * 16 B = 8192 B
}

// ---------------- Kernel A: bin particles + queries into buckets ----------------
__global__ __launch_bounds__(256) void bin_kernel(
    const float* __restrict__ rp, const float* __restrict__ pc,
    int* __restrict__ pCount, int* __restrict__ qCount,
    unsigned short* __restrict__ qIdx, float4* __restrict__ pBucket)
{
    const int gt = blockIdx.x * 256 + threadIdx.x;
    const int stride = gridDim.x * 256;
    for (int i = gt; i < NP; i += stride) {
        float x = pc[3*i], y = pc[3*i+1], z = pc[3*i+2];
        int cx = min(max((int)(x * 10.f), 0), 9);
        int cy = min(max((int)(y * 10.f), 0), 9);
        int cz = min(max((int)(z * 10.f), 0), 9);
        int c  = (cx * 10 + cy) * 10 + cz;
        int pos = atomicAdd(&pCount[c], 1);
        if (pos < CAP_P) pBucket[c * CAP_P + pos] = make_float4(x, y, z, __int_as_float(i));
    }
    for (int i = gt; i < NQ; i += stride) {
        float x = rp[3*i], y = rp[3*i+1], z = rp[3*i+2];
        int cx = min(max((int)(x * 10.f), 0), 9);
        int cy = min(max((int)(y * 10.f), 0), 9);
        int cz = min(max((int)(z * 10.f), 0), 9);
        int c  = (cx * 10 + cy) * 10 + cz;
        int pos = atomicAdd(&qCount[c], 1);
        if (pos < CAP_Q) qIdx[c * CAP_Q + pos] = (unsigned short)i;
    }
}

// ---------------- Kernel B: one block per cell, LDS-broadcast accumulation ----------------
__global__ __launch_bounds__(128) void cell_kernel(
    const float* __restrict__ rp,
    const int* __restrict__ pCount, const int* __restrict__ qCount,
    const unsigned short* __restrict__ qIdx, const float4* __restrict__ pBucket,
    float* __restrict__ out)
{
    __shared__ float4 nbr[NBR_CAP];     // 27-neighborhood particles, contiguous
    __shared__ float  sd2[NBR_CAP];     // rare-path d2 table
    __shared__ int    counts[27], ncell[27], offs[28];
    __shared__ int    nrare;
    __shared__ unsigned short rlist[CAP_Q];
    __shared__ float  ord[KNN][4];

    const int c   = blockIdx.x;
    const int tid = threadIdx.x;
    const int cz = c % 10, cy = (c / 10) % 10, cx = c / 100;

    // neighbor-cell counts
    if (tid < 27) {
        int dx = tid / 9 - 1, dy = (tid / 3) % 3 - 1, dz = tid % 3 - 1;
        int nx = cx + dx, ny = cy + dy, nz = cz + dz;
        bool valid = (unsigned)nx < 10u && (unsigned)ny < 10u && (unsigned)nz < 10u;
        int nc = valid ? (nx * 10 + ny) * 10 + nz : 0;
        ncell[tid]  = nc;
        counts[tid] = valid ? min(pCount[nc], CAP_P) : 0;
    }
    if (tid == 0) nrare = 0;
    __syncthreads();
    if (tid == 0) {
        int s = 0;
        for (int i = 0; i < 27; ++i) { offs[i] = s; s += counts[i]; }
        offs[27] = s;
    }
    __syncthreads();
    const int M = offs[27];

    // stage neighborhood into LDS (4 threads per neighbor cell)
    if (tid < 108) {
        int ci = tid >> 2, sub = tid & 3;
        int cnt = counts[ci], base = offs[ci], nc = ncell[ci];
        for (int e = sub; e < cnt; e += 4)
            nbr[base + e] = pBucket[nc * CAP_P + e];
    }
    __syncthreads();

    // ---- fast path: 4 threads per query, LDS broadcast reads ----
    const int nq = min(qCount[c], CAP_Q);
    const int sub = tid & 3;
    for (int i = tid >> 2; i < nq; i += 32) {
        const int qi = qIdx[c * CAP_Q + i];
        const float qx = rp[3*qi], qy = rp[3*qi+1], qz = rp[3*qi+2];
        float sw = 0.f, swx = 0.f, swy = 0.f, swz = 0.f;
        int cnt = 0;
        for (int j = sub; j < M; j += 4) {
            float4 pp = nbr[j];
            float dx = pp.x - qx, dy = pp.y - qy, dz = pp.z - qz;
            float d2 = fmaf(dx, dx, fmaf(dy, dy, dz * dz));
            float d  = sqrtf(d2);
            float w  = fmaxf(fmaf(d2 * d, -1000.f, 1.f), 0.f);  // 1-(d/R)^3, 0 outside
            sw  += w;
            swx = fmaf(w, pp.x, swx);
            swy = fmaf(w, pp.y, swy);
            swz = fmaf(w, pp.z, swz);
            cnt += (d2 <= R2) ? 1 : 0;
        }
        #pragma unroll
        for (int m = 1; m <= 2; m <<= 1) {
            sw  += __shfl_xor(sw,  m);
            swx += __shfl_xor(swx, m);
            swy += __shfl_xor(swy, m);
            swz += __shfl_xor(swz, m);
            cnt += __shfl_xor(cnt, m);
        }
        if (sub == 0) {
            if (cnt <= KNN) {
                // masked slots gather particle 0 then zero -> nn_d = ||q||
                float nq2 = fmaf(qx, qx, fmaf(qy, qy, qz * qz));
                float nqd = sqrtf(nq2);
                float w0  = fmaxf(fmaf(nq2 * nqd, -1000.f, 1.f), 0.f);
                float dens = sw + (float)(KNN - cnt) * w0;
                float inv  = 1.f / (dens + 1e-12f);
                ((float4*)out)[qi] = make_float4(swx * inv, swy * inv, swz * inv, dens);
            } else {
                int pos = atomicAdd(&nrare, 1);
                rlist[pos] = (unsigned short)qi;   // cap = CAP_Q, cannot overflow
            }
        }
    }
    __syncthreads();

    // ---- rare path (cnt > K): exact top-K by (d2, idx) lexicographic rank ----
    for (int r = 0; r < nrare; ++r) {          // block-uniform
        const int qi = rlist[r];
        const float qx = rp[3*qi], qy = rp[3*qi+1], qz = rp[3*qi+2];
        for (int j = tid; j < M; j += 128) {
            float4 pp = nbr[j];
            float dx = pp.x - qx, dy = pp.y - qy, dz = pp.z - qz;
            sd2[j] = fmaf(dx, dx, fmaf(dy, dy, dz * dz));
        }
        __syncthreads();
        for (int j = tid; j < M; j += 128) {
            float dj = sd2[j];
            if (dj <= R2) {
                int ij = __float_as_int(nbr[j].w);
                int rank = 0;
                for (int k = 0; k < M; ++k) {
                    float dk = sd2[k];
                    int   ik = __float_as_int(nbr[k].w);
                    rank += (dk < dj || (dk == dj && ik < ij)) ? 1 : 0;
                }
                if (rank < KNN) {               // exactly K entries land here
                    float4 pp = nbr[j];
                    float d = sqrtf(dj);
                    float w = fmaxf(fmaf(dj * d, -1000.f, 1.f), 0.f);
                    ord[rank][0] = w;
                    ord[rank][1] = w * pp.x;
                    ord[rank][2] = w * pp.y;
                    ord[rank][3] = w * pp.z;
                }
            }
        }
        __syncthreads();
        if (tid == 0) {
            float t0 = 0.f, t1 = 0.f, t2 = 0.f, t3 = 0.f;
            #pragma unroll
            for (int k = 0; k < KNN; ++k) {
                t0 += ord[k][0]; t1 += ord[k][1]; t2 += ord[k][2]; t3 += ord[k][3];
            }
            float inv = 1.f / (t0 + 1e-12f);    // cnt>K: m=0, no masked slots
            ((float4*)out)[qi] = make_float4(t1 * inv, t2 * inv, t3 * inv, t0);
        }
        __syncthreads();
    }
}

// ---------------- Fallback (validated round-1 monolithic) if ws too small ----------------
#define BLKQ   64
#define NWAVE  8
#define CHUNK  (NP / NWAVE)
#define THREADS (BLKQ * NWAVE)

__global__ __launch_bounds__(THREADS) void knn_smooth_kernel(
    const float* __restrict__ rp, const float* __restrict__ pc, float* __restrict__ out)
{
    __shared__ float4 sp[NP];
    __shared__ float  red[5][NWAVE][BLKQ];
    __shared__ int    sflag[BLKQ];
    __shared__ int    scnt;
    __shared__ float  ord[KNN][4];

    const int tid = threadIdx.x, lane = tid & 63, wv = tid >> 6, blk = blockIdx.x;
    float* spf = (float*)sp;
    for (int i = tid; i < NP * 3; i += THREADS) {
        int p = i / 3, ccc = i - 3 * p;
        spf[4 * p + ccc] = pc[i];
    }
    __syncthreads();
    const int q = blk * BLKQ + lane;
    const float qx = rp[3*q], qy = rp[3*q+1], qz = rp[3*q+2];
    float sw = 0.f, swx = 0.f, swy = 0.f, swz = 0.f; int cnt = 0;
    const int p0 = wv * CHUNK;
    #pragma unroll 4
    for (int p = p0; p < p0 + CHUNK; ++p) {
        float4 pp = sp[p];
        float dx = pp.x - qx, dy = pp.y - qy, dz = pp.z - qz;
        float d2 = fmaf(dx, dx, fmaf(dy, dy, dz * dz));
        if (d2 <= R2) {
            float d = sqrtf(d2);
            float w = fmaxf(fmaf(d2 * d, -1000.f, 1.f), 0.f);
            cnt += 1; sw += w;
            swx = fmaf(w, pp.x, swx); swy = fmaf(w, pp.y, swy); swz = fmaf(w, pp.z, swz);
        }
    }
    red[0][wv][lane] = sw; red[1][wv][lane] = swx; red[2][wv][lane] = swy;
    red[3][wv][lane] = swz; red[4][wv][lane] = (float)cnt;
    __syncthreads();
    if (tid < BLKQ) {
        float tsw = 0.f, tswx = 0.f, tswy = 0.f, tswz = 0.f; int tc = 0;
        #pragma unroll
        for (int w = 0; w < NWAVE; ++w) {
            tsw += red[0][w][tid]; tswx += red[1][w][tid]; tswy += red[2][w][tid];
            tswz += red[3][w][tid]; tc += (int)red[4][w][tid];
        }
        int flagged = (tc > KNN) ? 1 : 0;
        sflag[tid] = flagged;
        if (!flagged) {
            float nq2 = fmaf(qx, qx, fmaf(qy, qy, qz * qz));
            float nqd = sqrtf(nq2);
            float w0 = fmaxf(fmaf(nq2 * nqd, -1000.f, 1.f), 0.f);
            float dens = tsw + (float)(KNN - tc) * w0;
            float inv = 1.f / (dens + 1e-12f);
            ((float4*)out)[q] = make_float4(tswx * inv, tswy * inv, tswz * inv, dens);
        }
    }
    __syncthreads();
    float* sd2 = &red[0][0][0];
    int*   sid = (int*)(sd2 + 1024);
    for (int f = 0; f < BLKQ; ++f) {
        if (!sflag[f]) continue;
        if (tid == 0) scnt = 0;
        __syncthreads();
        const int fq = blk * BLKQ + f;
        const float fx = rp[3*fq], fy = rp[3*fq+1], fz = rp[3*fq+2];
        for (int p = tid; p < NP; p += THREADS) {
            float4 pp = sp[p];
            float dx = pp.x - fx, dy = pp.y - fy, dz = pp.z - fz;
            float d2 = fmaf(dx, dx, fmaf(dy, dy, dz * dz));
            if (d2 <= R2) {
                int pos = atomicAdd(&scnt, 1);
                if (pos < 1024) { sd2[pos] = d2; sid[pos] = p; }
            }
        }
        __syncthreads();
        const int ne = (scnt < 1024) ? scnt : 1024;
        for (int e = tid; e < ne; e += THREADS) {
            float myd = sd2[e]; int myi = sid[e]; int rank = 0;
            for (int j = 0; j < ne; ++j) {
                float dj = sd2[j]; int ij = sid[j];
                rank += (dj < myd || (dj == myd && ij < myi)) ? 1 : 0;
            }
            if (rank < KNN) {
                float4 pp = sp[myi];
                float d = sqrtf(myd);
                float w = fmaxf(fmaf(myd * d, -1000.f, 1.f), 0.f);
                ord[rank][0] = w; ord[rank][1] = w * pp.x;
                ord[rank][2] = w * pp.y; ord[rank][3] = w * pp.z;
            }
        }
        __syncthreads();
        if (tid == 0) {
            float t0 = 0.f, t1 = 0.f, t2 = 0.f, t3 = 0.f;
            #pragma unroll
            for (int k = 0; k < KNN; ++k) {
                t0 += ord[k][0]; t1 += ord[k][1]; t2 += ord[k][2]; t3 += ord[k][3];
            }
            float inv = 1.f / (t0 + 1e-12f);
            ((float4*)out)[fq] = make_float4(t1 * inv, t2 * inv, t3 * inv, t0);
        }
        __syncthreads();
    }
}

extern "C" void kernel_launch(void* const* d_in, const int* in_sizes, int n_in,
                              void* d_out, int out_size, void* d_ws, size_t ws_size,
                              hipStream_t stream) {
    const float* rp  = (const float*)d_in[0];   // [512,64,3]
    const float* pc  = (const float*)d_in[1];   // [4096,3]
    float*       out = (float*)d_out;           // [512,64,4]

    if (ws_size < WS_NEEDED) {
        knn_smooth_kernel<<<NQ / BLKQ, THREADS, 0, stream>>>(rp, pc, out);
        return;
    }

    int*            pCount  = (int*)d_ws;                             // +0
    int*            qCount  = (int*)((char*)d_ws + 4096);             // +4096
    unsigned short* qIdx    = (unsigned short*)((char*)d_ws + 8192);  // +8192
    float4*         pBucket = (float4*)((char*)d_ws + 200704);        // +200704

    zero_kernel<<<1,    512, 0, stream>>>((int4*)d_ws);
    bin_kernel <<<64,   256, 0, stream>>>(rp, pc, pCount, qCount, qIdx, pBucket);
    cell_kernel<<<NCELLS, 128, 0, stream>>>(rp, pCount, qCount, qIdx, pBucket, out);
}